// Round 6
// baseline (10.177 us; speedup 1.0000x reference)
//
#include <hip/hip_runtime.h>

#define T_LEN 4096
#define BLOCK 512
#define EPT 8            // elements per thread = T_LEN / BLOCK
#define NWAVES 8         // BLOCK / 64
#define RADIUS_I 20
#define NROWS 8

// One block per row; last block to finish (device-scope atomic counter)
// performs the final combine. Counter correctness is independent of its
// initial value: each call adds exactly NROWS, and any NROWS consecutive
// integers contain exactly one value == NROWS-1 (mod NROWS).
__global__ __launch_bounds__(BLOCK)
void aml_row_kernel(const float* __restrict__ vel,
                    const int* __restrict__ bnd,
                    const int* __restrict__ msk,
                    float* __restrict__ partials,       // [2 * NROWS] in d_ws
                    unsigned int* __restrict__ counter, // in d_ws
                    float* __restrict__ out) {
    const int row  = blockIdx.x;
    const int tid  = threadIdx.x;
    const int lane = tid & 63;
    const int wave = tid >> 6;

    __shared__ unsigned long long sbm[T_LEN / 64];  // boundary bitmask
    __shared__ float swsum[NWAVES];
    __shared__ float sredN[NWAVES];
    __shared__ float sredD[NWAVES];

    const size_t rowoff = (size_t)row * T_LEN + (size_t)tid * EPT;
    const float4* vp = reinterpret_cast<const float4*>(vel + rowoff);
    const int4*   bp = reinterpret_cast<const int4*>(bnd + rowoff);
    const int4*   mp = reinterpret_cast<const int4*>(msk + rowoff);

    const float4 v4a = vp[0], v4b = vp[1];
    const int4   b4a = bp[0], b4b = bp[1];
    const int4   m4a = mp[0], m4b = mp[1];

    float vv[EPT], mf[EPT];
    int be[EPT];
    unsigned long long nib = 0ULL;
    {
        const float vs[EPT] = {v4a.x, v4a.y, v4a.z, v4a.w, v4b.x, v4b.y, v4b.z, v4b.w};
        const int   bs[EPT] = {b4a.x, b4a.y, b4a.z, b4a.w, b4b.x, b4b.y, b4b.z, b4b.w};
        const int   ms[EPT] = {m4a.x, m4a.y, m4a.z, m4a.w, m4b.x, m4b.y, m4b.z, m4b.w};
#pragma unroll
        for (int i = 0; i < EPT; ++i) {
            mf[i] = ms[i] ? 1.0f : 0.0f;
            vv[i] = vs[i] * mf[i];
            be[i] = (bs[i] != 0 || ms[i] == 0) ? 1 : 0;
            nib |= ((unsigned long long)be[i]) << i;
        }
    }

    // ---- build boundary bitmask: 8 threads per 64-bit word ----
    unsigned long long wbits = nib << ((tid & 7) * 8);
#pragma unroll
    for (int off = 1; off < 8; off <<= 1)
        wbits |= __shfl_xor(wbits, off, 64);
    if ((tid & 7) == 0) sbm[tid >> 3] = wbits;
    __syncthreads();

    // ---- block-wide inclusive prefix sum (cumsum) ----
    float p[EPT];
    p[0] = vv[0];
#pragma unroll
    for (int i = 1; i < EPT; ++i) p[i] = p[i - 1] + vv[i];
    const float tsum = p[EPT - 1];

    float sc = tsum;
#pragma unroll
    for (int off = 1; off < 64; off <<= 1) {
        float n = __shfl_up(sc, off, 64);
        if (lane >= off) sc += n;
    }
    if (lane == 63) swsum[wave] = sc;
    __syncthreads();

    if (wave == 0 && lane < NWAVES) {
        float w = swsum[lane];
#pragma unroll
        for (int off = 1; off < NWAVES; off <<= 1) {
            float n = __shfl_up(w, off, 64);
            if (lane >= off) w += n;
        }
        swsum[lane] = w;
    }
    __syncthreads();

    const float base = (wave == 0) ? 0.0f : swsum[wave - 1];
    const float lane_excl = sc - tsum;

    // ---- distance transform via bitmask (clamped at 20) ----
    const int wi = tid >> 3;
    const unsigned long long W0  = sbm[wi];
    const unsigned long long Wm1 = (wi > 0) ? sbm[wi - 1] : 0ULL;
    const unsigned long long Wp1 = (wi < T_LEN / 64 - 1) ? sbm[wi + 1] : 0ULL;

    float num = 0.0f, den = 0.0f, dmax = 0.0f;
#pragma unroll
    for (int i = 0; i < EPT; ++i) {
        const int t   = tid * EPT + i;
        const int pos = t & 63;
        float gtv;
        if (be[i]) {
            gtv = 0.0f;
        } else {
            int d = min(t + 1, T_LEN - t);   // virtual boundaries at -1 and T
            const unsigned long long low = (pos == 0) ? 0ULL
                                         : (W0 & ((1ULL << pos) - 1ULL));
            if (low) {
                d = min(d, pos - (63 - __builtin_clzll(low)));
            } else if (Wm1) {
                d = min(d, pos + 1 + __builtin_clzll(Wm1));
            }
            const unsigned long long high = (W0 >> pos) >> 1;
            if (high) {
                d = min(d, __builtin_ctzll(high) + 1);
            } else if (Wp1) {
                d = min(d, 64 - pos + __builtin_ctzll(Wp1));
            }
            gtv = (float)min(d, RADIUS_I);
        }
        dmax = fmaxf(dmax, gtv);
        const float pred = base + lane_excl + p[i];
        num += fabsf(pred - gtv) * mf[i];
        den += mf[i];
    }

    // ---- wave reductions ----
#pragma unroll
    for (int off = 32; off > 0; off >>= 1) {
        num += __shfl_xor(num, off, 64);
        den += __shfl_xor(den, off, 64);
        dmax = fmaxf(dmax, __shfl_xor(dmax, off, 64));
    }
    if (lane == 0) { sredN[wave] = num; sredD[wave] = den; swsum[wave] = dmax; }
    __syncthreads();

    // ---- epilogue: wave 0 only, lane-parallel ----
    if (wave == 0) {
        float ns = (lane < NWAVES) ? sredN[lane] : 0.0f;
        float ds = (lane < NWAVES) ? sredD[lane] : 0.0f;
        float mx = (lane < NWAVES) ? swsum[lane] : 0.0f;
#pragma unroll
        for (int off = NWAVES / 2; off > 0; off >>= 1) {
            ns += __shfl_xor(ns, off, 64);
            ds += __shfl_xor(ds, off, 64);
            mx = fmaxf(mx, __shfl_xor(mx, off, 64));
        }
        const float scale = mx + 1e-6f;

        unsigned int old = 0;
        if (lane == 0) {
            __hip_atomic_store(&partials[row], ns / scale,
                               __ATOMIC_RELAXED, __HIP_MEMORY_SCOPE_AGENT);
            __hip_atomic_store(&partials[NROWS + row], ds,
                               __ATOMIC_RELAXED, __HIP_MEMORY_SCOPE_AGENT);
            old = __hip_atomic_fetch_add(counter, 1u,
                               __ATOMIC_ACQ_REL, __HIP_MEMORY_SCOPE_AGENT);
        }
        old = __shfl(old, 0, 64);
        if ((old % NROWS) == NROWS - 1) {
            // last block: 16 lanes load 16 partials in parallel (relaxed;
            // ordered by the ACQ_REL fetch_add above)
            float v = (lane < 2 * NROWS)
                    ? __hip_atomic_load(&partials[lane],
                          __ATOMIC_RELAXED, __HIP_MEMORY_SCOPE_AGENT)
                    : 0.0f;
            float num_all = (lane < NROWS) ? v : 0.0f;
            float den_all = (lane >= NROWS && lane < 2 * NROWS) ? v : 0.0f;
#pragma unroll
            for (int off = 8; off > 0; off >>= 1) {
                num_all += __shfl_xor(num_all, off, 64);
                den_all += __shfl_xor(den_all, off, 64);
            }
            if (lane == 0) out[0] = num_all / (den_all + 1e-6f);
        }
    }
}

extern "C" void kernel_launch(void* const* d_in, const int* in_sizes, int n_in,
                              void* d_out, int out_size, void* d_ws, size_t ws_size,
                              hipStream_t stream) {
    const float* vel = (const float*)d_in[0];
    const int*   bnd = (const int*)d_in[1];
    const int*   msk = (const int*)d_in[2];
    (void)in_sizes; (void)n_in; (void)ws_size; (void)out_size;

    float* partials = (float*)d_ws;                       // 16 floats
    unsigned int* counter = (unsigned int*)((char*)d_ws + 64);

    aml_row_kernel<<<NROWS, BLOCK, 0, stream>>>(vel, bnd, msk, partials,
                                                counter, (float*)d_out);
}